// Round 1
// baseline (768.785 us; speedup 1.0000x reference)
//
#include <hip/hip_runtime.h>
#include <hip/hip_bf16.h>
#include <stdint.h>

// MoE: B=4,S=2048,D=1024,E=8,TOPK=2,I=938. Sparse top-2 routing + bf16 MFMA GEMMs.

typedef __bf16 bf16_t;
typedef __bf16 bf16x8 __attribute__((ext_vector_type(8)));
typedef float  f32x4  __attribute__((ext_vector_type(4)));

#define TOKENS    8192
#define DMODEL    1024
#define NEXP      8
#define INTER     938
#define IPAD      960      // INTER padded to multiple of 64 (K of GEMM2, zero-padded)
#define GU_ROWS   1876     // 2*INTER
#define CAP_ROWS  17408    // worst-case padded routed rows: 16384 + 8*128
#define MAX_TILES 136      // CAP_ROWS / 128

#define BM 128
#define BN 64
#define BK 64

// ---- async global->LDS, 16B per lane; LDS dest is wave-uniform base + lane*16 ----
__device__ __forceinline__ void async16(const bf16_t* g, bf16_t* l) {
  __builtin_amdgcn_global_load_lds(
      (__attribute__((address_space(1))) void*)(g),
      (__attribute__((address_space(3))) void*)(l),
      16, 0, 0);
}

// ---------------- converts ----------------
__device__ __forceinline__ unsigned short f2bu(float f) {
  bf16_t b = (bf16_t)f;
  unsigned short u;
  __builtin_memcpy(&u, &b, 2);
  return u;
}

__global__ void conv_f2b(const float4* __restrict__ s, ushort4* __restrict__ d, int n4) {
  int i = blockIdx.x * 256 + threadIdx.x;
  if (i >= n4) return;
  float4 v = s[i];
  ushort4 r;
  r.x = f2bu(v.x); r.y = f2bu(v.y); r.z = f2bu(v.z); r.w = f2bu(v.w);
  d[i] = r;
}

// down: src [rows,938] fp32 -> dst [rows,960] bf16, cols 938..959 zeroed
__global__ void conv_down(const float* __restrict__ s, bf16_t* __restrict__ d, int rows) {
  int i = blockIdx.x * 256 + threadIdx.x;
  int total = rows * IPAD;
  if (i >= total) return;
  int r = i / IPAD, c = i - r * IPAD;
  float v = (c < INTER) ? s[(size_t)r * INTER + c] : 0.f;
  d[i] = (bf16_t)v;
}

// ---------------- routing plumbing ----------------
__global__ void init_kernel(int* __restrict__ row_token, int* __restrict__ counts,
                            int* __restrict__ cursor) {
  int i = blockIdx.x * 256 + threadIdx.x;
  if (i < CAP_ROWS) row_token[i] = -1;
  if (i < NEXP) { counts[i] = 0; cursor[i] = 0; }
}

// one wave per token: fp32 logits, softmax, top-2 (jax tie-break: lower index wins)
__global__ __launch_bounds__(256) void router_kernel(
    const float* __restrict__ X, const float* __restrict__ GW,
    int* __restrict__ e01, float* __restrict__ w01, int* __restrict__ counts) {
  int token = blockIdx.x * 4 + (threadIdx.x >> 6);
  int lane = threadIdx.x & 63;
  const float* x = X + (size_t)token * DMODEL;
  float acc[NEXP];
#pragma unroll
  for (int e = 0; e < NEXP; e++) acc[e] = 0.f;
  for (int d = lane; d < DMODEL; d += 64) {
    float xv = x[d];
#pragma unroll
    for (int e = 0; e < NEXP; e++) acc[e] += xv * GW[e * DMODEL + d];
  }
#pragma unroll
  for (int e = 0; e < NEXP; e++) {
#pragma unroll
    for (int off = 32; off > 0; off >>= 1) acc[e] += __shfl_down(acc[e], off, 64);
  }
  if (lane == 0) {
    float mx = acc[0];
#pragma unroll
    for (int e = 1; e < NEXP; e++) mx = fmaxf(mx, acc[e]);
    float p[NEXP]; float s = 0.f;
#pragma unroll
    for (int e = 0; e < NEXP; e++) { p[e] = expf(acc[e] - mx); s += p[e]; }
    int i0 = 0;
#pragma unroll
    for (int e = 1; e < NEXP; e++) if (p[e] > p[i0]) i0 = e;
    int i1 = (i0 == 0) ? 1 : 0;
#pragma unroll
    for (int e = 0; e < NEXP; e++) if (e != i1 && e != i0 && p[e] > p[i1]) i1 = e;
    float p0 = p[i0] / s, p1 = p[i1] / s;
    float inv = 1.f / (p0 + p1 + 1e-8f);
    e01[token * 2 + 0] = i0; e01[token * 2 + 1] = i1;
    w01[token * 2 + 0] = p0 * inv; w01[token * 2 + 1] = p1 * inv;
    atomicAdd(&counts[i0], 1); atomicAdd(&counts[i1], 1);
  }
}

__global__ void offsets_kernel(const int* __restrict__ counts, int* __restrict__ off,
                               int* __restrict__ tileExpert, int* __restrict__ nTiles) {
  if (threadIdx.x != 0 || blockIdx.x != 0) return;
  int o = 0, t = 0;
  for (int e = 0; e < NEXP; e++) {
    off[e] = o;
    int pad = (counts[e] + BM - 1) / BM * BM;
    for (int i = 0; i < pad / BM; i++) tileExpert[t++] = e;
    o += pad;
  }
  off[NEXP] = o;
  *nTiles = t;
}

__global__ void scatter_kernel(const int* __restrict__ e01, const float* __restrict__ w01,
                               const int* __restrict__ off, int* __restrict__ cursor,
                               int* __restrict__ row_token, float* __restrict__ row_weight) {
  int t = blockIdx.x * 256 + threadIdx.x;
  if (t >= TOKENS) return;
#pragma unroll
  for (int s = 0; s < 2; s++) {
    int e = e01[t * 2 + s];
    int pos = off[e] + atomicAdd(&cursor[e], 1);
    row_token[pos] = t;
    row_weight[pos] = w01[t * 2 + s];
  }
}

// ---------------- GEMM1: A[M,960] = swiglu(X @ Wgu^T), fused gate/up ----------------
// X bf16 [8192,1024]; Wgu bf16 row-major [*,1024] (gate rows f, up rows 938+f)
// tile: 128 tokens x 64 features, BK=64; 4 waves as 2x2, wave = 64x32
__global__ __launch_bounds__(256) void gemm1_swiglu(
    const bf16_t* __restrict__ Xb, const bf16_t* __restrict__ Wgu, long wStride,
    bf16_t* __restrict__ Aout, const int* __restrict__ row_token,
    const int* __restrict__ tileExpert, const int* __restrict__ nTilesPtr) {
  const int mtile = blockIdx.x;
  if (nTilesPtr && mtile >= *nTilesPtr) return;
  const int m0 = mtile * BM;
  const int f0 = blockIdx.y * BN;

  __shared__ bf16_t sA[BM * BK];   // 16KB
  __shared__ bf16_t sBg[BN * BK];  // 8KB
  __shared__ bf16_t sBu[BN * BK];  // 8KB

  const int tid = threadIdx.x;
  const int w = tid >> 6, lane = tid & 63;
  const bf16_t* W = Wgu + (tileExpert ? (long)tileExpert[mtile] * wStride : 0);

  // staging descriptors (rows fixed across K-steps)
  const bf16_t* aptr[4];
#pragma unroll
  for (int i = 0; i < 4; i++) {
    int q = (i * 4 + w) * 64 + lane;          // chunk 0..1023
    int row = q >> 3, cc = (q & 7) * 8;
    int tok = m0 + row;
    if (row_token) { int t = row_token[tok]; tok = (t < 0) ? 0 : t; }
    aptr[i] = Xb + (size_t)tok * DMODEL + cc;
  }
  const bf16_t* bgp[2]; const bf16_t* bup[2];
#pragma unroll
  for (int i = 0; i < 2; i++) {
    int q = (i * 4 + w) * 64 + lane;          // chunk 0..511
    int r = q >> 3, cc = (q & 7) * 8;
    bgp[i] = W + (size_t)(f0 + r) * DMODEL + cc;
    bup[i] = W + (size_t)(INTER + f0 + r) * DMODEL + cc;  // may overrun into pad: safe
  }

  f32x4 accG[4][2], accU[4][2];
#pragma unroll
  for (int mi = 0; mi < 4; mi++)
#pragma unroll
    for (int ni = 0; ni < 2; ni++) {
      accG[mi][ni] = (f32x4){0.f, 0.f, 0.f, 0.f};
      accU[mi][ni] = (f32x4){0.f, 0.f, 0.f, 0.f};
    }

  const int wm = w >> 1, wn = w & 1;
  const int lr = lane & 15, quad = lane >> 4;

  for (int k0 = 0; k0 < DMODEL; k0 += BK) {
#pragma unroll
    for (int i = 0; i < 4; i++) async16(aptr[i] + k0, &sA[(i * 4 + w) * 512]);
#pragma unroll
    for (int i = 0; i < 2; i++) {
      async16(bgp[i] + k0, &sBg[(i * 4 + w) * 512]);
      async16(bup[i] + k0, &sBu[(i * 4 + w) * 512]);
    }
    __syncthreads();
#pragma unroll
    for (int kk = 0; kk < BK; kk += 32) {
      bf16x8 av[4], bg[2], bu[2];
#pragma unroll
      for (int mi = 0; mi < 4; mi++)
        av[mi] = *(const bf16x8*)&sA[(wm * 64 + mi * 16 + lr) * BK + kk + quad * 8];
#pragma unroll
      for (int ni = 0; ni < 2; ni++) {
        bg[ni] = *(const bf16x8*)&sBg[(wn * 32 + ni * 16 + lr) * BK + kk + quad * 8];
        bu[ni] = *(const bf16x8*)&sBu[(wn * 32 + ni * 16 + lr) * BK + kk + quad * 8];
      }
#pragma unroll
      for (int mi = 0; mi < 4; mi++)
#pragma unroll
        for (int ni = 0; ni < 2; ni++) {
          accG[mi][ni] = __builtin_amdgcn_mfma_f32_16x16x32_bf16(av[mi], bg[ni], accG[mi][ni], 0, 0, 0);
          accU[mi][ni] = __builtin_amdgcn_mfma_f32_16x16x32_bf16(av[mi], bu[ni], accU[mi][ni], 0, 0, 0);
        }
    }
    __syncthreads();
  }

  // epilogue: C/D layout col=lane&15, row=quad*4+reg  (verified m89/m91)
#pragma unroll
  for (int mi = 0; mi < 4; mi++)
#pragma unroll
    for (int ni = 0; ni < 2; ni++)
#pragma unroll
      for (int r = 0; r < 4; r++) {
        int row = m0 + wm * 64 + mi * 16 + quad * 4 + r;
        int col = f0 + wn * 32 + ni * 16 + lr;
        float g = accG[mi][ni][r], u = accU[mi][ni][r];
        float v = (col < INTER) ? (g / (1.f + __expf(-g))) * u : 0.f;
        Aout[(size_t)row * IPAD + col] = (bf16_t)v;
      }
}

// ---------------- GEMM2: Out[M,1024] (+)= A[M,960] @ Wd^T ----------------
__global__ __launch_bounds__(256) void gemm2(
    const bf16_t* __restrict__ Ain, const bf16_t* __restrict__ Wd, long wStride,
    float* __restrict__ Out, const int* __restrict__ row_token,
    const float* __restrict__ row_weight, const int* __restrict__ tileExpert,
    const int* __restrict__ nTilesPtr) {
  const int mtile = blockIdx.x;
  if (nTilesPtr && mtile >= *nTilesPtr) return;
  const int m0 = mtile * BM;
  const int n0 = blockIdx.y * BN;

  __shared__ bf16_t sA[BM * BK];
  __shared__ bf16_t sB[BN * BK];

  const int tid = threadIdx.x;
  const int w = tid >> 6, lane = tid & 63;
  const bf16_t* W = Wd + (tileExpert ? (long)tileExpert[mtile] * wStride : 0);

  const bf16_t* aptr[4];
#pragma unroll
  for (int i = 0; i < 4; i++) {
    int q = (i * 4 + w) * 64 + lane;
    int row = q >> 3, cc = (q & 7) * 8;
    aptr[i] = Ain + (size_t)(m0 + row) * IPAD + cc;
  }
  const bf16_t* bp[2];
#pragma unroll
  for (int i = 0; i < 2; i++) {
    int q = (i * 4 + w) * 64 + lane;
    int r = q >> 3, cc = (q & 7) * 8;
    bp[i] = W + (size_t)(n0 + r) * IPAD + cc;
  }

  f32x4 acc[4][2];
#pragma unroll
  for (int mi = 0; mi < 4; mi++)
#pragma unroll
    for (int ni = 0; ni < 2; ni++) acc[mi][ni] = (f32x4){0.f, 0.f, 0.f, 0.f};

  const int wm = w >> 1, wn = w & 1;
  const int lr = lane & 15, quad = lane >> 4;

  for (int k0 = 0; k0 < IPAD; k0 += BK) {
#pragma unroll
    for (int i = 0; i < 4; i++) async16(aptr[i] + k0, &sA[(i * 4 + w) * 512]);
#pragma unroll
    for (int i = 0; i < 2; i++) async16(bp[i] + k0, &sB[(i * 4 + w) * 512]);
    __syncthreads();
#pragma unroll
    for (int kk = 0; kk < BK; kk += 32) {
      bf16x8 av[4], bv[2];
#pragma unroll
      for (int mi = 0; mi < 4; mi++)
        av[mi] = *(const bf16x8*)&sA[(wm * 64 + mi * 16 + lr) * BK + kk + quad * 8];
#pragma unroll
      for (int ni = 0; ni < 2; ni++)
        bv[ni] = *(const bf16x8*)&sB[(wn * 32 + ni * 16 + lr) * BK + kk + quad * 8];
#pragma unroll
      for (int mi = 0; mi < 4; mi++)
#pragma unroll
        for (int ni = 0; ni < 2; ni++)
          acc[mi][ni] = __builtin_amdgcn_mfma_f32_16x16x32_bf16(av[mi], bv[ni], acc[mi][ni], 0, 0, 0);
    }
    __syncthreads();
  }

#pragma unroll
  for (int mi = 0; mi < 4; mi++)
#pragma unroll
    for (int ni = 0; ni < 2; ni++)
#pragma unroll
      for (int r = 0; r < 4; r++) {
        int row = m0 + wm * 64 + mi * 16 + quad * 4 + r;
        int col = n0 + wn * 32 + ni * 16 + lr;
        float v = acc[mi][ni][r];
        if (!row_token) {
          Out[(size_t)row * DMODEL + col] = v;          // shared expert: plain store
        } else {
          int t = row_token[row];
          if (t >= 0) atomicAdd(&Out[(size_t)t * DMODEL + col], row_weight[row] * v);
        }
      }
}

// ---------------- launch ----------------
extern "C" void kernel_launch(void* const* d_in, const int* in_sizes, int n_in,
                              void* d_out, int out_size, void* d_ws, size_t ws_size,
                              hipStream_t stream) {
  const float* X   = (const float*)d_in[0];
  const float* GW  = (const float*)d_in[1];
  const float* SGU = (const float*)d_in[2];
  const float* SD  = (const float*)d_in[3];
  const float* EGU = (const float*)d_in[4];
  const float* ED  = (const float*)d_in[5];
  float* Out = (float*)d_out;

  char* ws = (char*)d_ws;
  size_t o = 0;
  auto alloc = [&](size_t b) -> char* {
    char* p = ws + o;
    o = (o + b + 255) & ~(size_t)255;
    return p;
  };
  bf16_t* Xb     = (bf16_t*)alloc((size_t)TOKENS * DMODEL * 2);          // 16.8 MB
  bf16_t* WguS   = (bf16_t*)alloc((size_t)1920 * DMODEL * 2);           // pad rows for up-overrun
  bf16_t* WdS    = (bf16_t*)alloc((size_t)DMODEL * IPAD * 2);
  bf16_t* WguE   = (bf16_t*)alloc((size_t)NEXP * GU_ROWS * DMODEL * 2 + 65536);
  bf16_t* WdE    = (bf16_t*)alloc((size_t)NEXP * DMODEL * IPAD * 2);
  bf16_t* As     = (bf16_t*)alloc((size_t)TOKENS * IPAD * 2);
  bf16_t* Ar     = (bf16_t*)alloc((size_t)CAP_ROWS * IPAD * 2);
  int*    e01    = (int*)alloc(TOKENS * 2 * 4);
  float*  w01    = (float*)alloc(TOKENS * 2 * 4);
  int*    counts = (int*)alloc(64);
  int*    cursor = (int*)alloc(64);
  int*    off    = (int*)alloc(64);
  int*    nTiles = (int*)alloc(64);
  int*    tileEx = (int*)alloc(MAX_TILES * 4);
  int*    rowTok = (int*)alloc(CAP_ROWS * 4);
  float*  rowW   = (float*)alloc(CAP_ROWS * 4);
  (void)ws_size; (void)in_sizes; (void)n_in; (void)out_size;

  // bf16 conversions (re-done every call: ws is re-poisoned)
  conv_f2b<<<(2097152 + 255) / 256, 256, 0, stream>>>((const float4*)X, (ushort4*)Xb, 2097152);
  conv_f2b<<<(480256 + 255) / 256, 256, 0, stream>>>((const float4*)SGU, (ushort4*)WguS, 480256);
  conv_f2b<<<(3842048 + 255) / 256, 256, 0, stream>>>((const float4*)EGU, (ushort4*)WguE, 3842048);
  conv_down<<<(DMODEL * IPAD + 255) / 256, 256, 0, stream>>>(SD, WdS, DMODEL);
  conv_down<<<(NEXP * DMODEL * IPAD + 255) / 256, 256, 0, stream>>>(ED, WdE, NEXP * DMODEL);

  // routing
  init_kernel<<<(CAP_ROWS + 255) / 256, 256, 0, stream>>>(rowTok, counts, cursor);
  router_kernel<<<TOKENS / 4, 256, 0, stream>>>(X, GW, e01, w01, counts);
  offsets_kernel<<<1, 1, 0, stream>>>(counts, off, tileEx, nTiles);
  scatter_kernel<<<TOKENS / 256, 256, 0, stream>>>(e01, w01, off, cursor, rowTok, rowW);

  // GEMMs
  gemm1_swiglu<<<dim3(TOKENS / BM, IPAD / BN), 256, 0, stream>>>(
      Xb, WguS, 0, As, nullptr, nullptr, nullptr);
  gemm1_swiglu<<<dim3(MAX_TILES, IPAD / BN), 256, 0, stream>>>(
      Xb, WguE, (long)GU_ROWS * DMODEL, Ar, rowTok, tileEx, nTiles);
  gemm2<<<dim3(TOKENS / BM, DMODEL / BN), 256, 0, stream>>>(
      As, WdS, 0, Out, nullptr, nullptr, nullptr, nullptr);
  gemm2<<<dim3(MAX_TILES, DMODEL / BN), 256, 0, stream>>>(
      Ar, WdE, (long)DMODEL * IPAD, Out, rowTok, rowW, tileEx, nTiles);
}

// Round 2
// 520.610 us; speedup vs baseline: 1.4767x; 1.4767x over previous
//
#include <hip/hip_runtime.h>
#include <hip/hip_bf16.h>
#include <stdint.h>

// MoE: B=4,S=2048,D=1024,E=8,TOPK=2,I=938. Sparse top-2 routing + bf16 MFMA GEMMs.
// R2: router rewritten (ILP float4 loads, no atomics, fused X->bf16 emit);
//     histogram/scan-based token bucketing (no contended global atomics).

typedef __bf16 bf16_t;
typedef __bf16 bf16x8 __attribute__((ext_vector_type(8)));
typedef float  f32x4  __attribute__((ext_vector_type(4)));

#define TOKENS    8192
#define DMODEL    1024
#define NEXP      8
#define INTER     938
#define IPAD      960      // INTER padded to multiple of 64 (K of GEMM2, zero-padded)
#define GU_ROWS   1876     // 2*INTER
#define CAP_ROWS  17408    // worst-case padded routed rows: 16384 + 8*128
#define MAX_TILES 136      // CAP_ROWS / 128

#define BM 128
#define BN 64
#define BK 64

#define PLAN_BLOCKS 16
#define TOK_PER_PLAN (TOKENS / PLAN_BLOCKS)   // 512 tokens, 1024 assignments / block

// ---- async global->LDS, 16B per lane; LDS dest is wave-uniform base + lane*16 ----
__device__ __forceinline__ void async16(const bf16_t* g, bf16_t* l) {
  __builtin_amdgcn_global_load_lds(
      (__attribute__((address_space(1))) void*)(g),
      (__attribute__((address_space(3))) void*)(l),
      16, 0, 0);
}

// ---------------- converts ----------------
__device__ __forceinline__ unsigned short f2bu(float f) {
  bf16_t b = (bf16_t)f;
  unsigned short u;
  __builtin_memcpy(&u, &b, 2);
  return u;
}

__global__ void conv_f2b(const float4* __restrict__ s, ushort4* __restrict__ d, int n4) {
  int i = blockIdx.x * 256 + threadIdx.x;
  if (i >= n4) return;
  float4 v = s[i];
  ushort4 r;
  r.x = f2bu(v.x); r.y = f2bu(v.y); r.z = f2bu(v.z); r.w = f2bu(v.w);
  d[i] = r;
}

// down: src [rows,938] fp32 -> dst [rows,960] bf16, cols 938..959 zeroed
// linear c-major index: scalar loads/stores coalesced across lanes
__global__ void conv_down(const float* __restrict__ s, bf16_t* __restrict__ d, int rows) {
  int i = blockIdx.x * 256 + threadIdx.x;
  int total = rows * IPAD;
  if (i >= total) return;
  int r = i / IPAD, c = i - r * IPAD;
  float v = (c < INTER) ? s[(size_t)r * INTER + c] : 0.f;
  d[i] = (bf16_t)v;
}

// ---------------- routing ----------------
__global__ void init_kernel(int* __restrict__ row_token) {
  int i = blockIdx.x * 256 + threadIdx.x;
  if (i < CAP_ROWS) row_token[i] = -1;
}

// one wave per token: fp32 logits with full ILP, top-2, NO atomics.
// Also emits Xb (bf16 copy of X) since the row is already in registers.
__global__ __launch_bounds__(256) void router_kernel(
    const float4* __restrict__ X4, const float4* __restrict__ GW4,
    bf16_t* __restrict__ Xb, int* __restrict__ e01, float* __restrict__ w01) {
  int token = blockIdx.x * 4 + (threadIdx.x >> 6);
  int lane = threadIdx.x & 63;
  const float4* x4 = X4 + (size_t)token * 256;

  float4 xv[4];
#pragma unroll
  for (int j = 0; j < 4; j++) xv[j] = x4[lane + 64 * j];

  // emit bf16 row (saves the separate X conversion pass)
  ushort4* xbrow = (ushort4*)(Xb + (size_t)token * DMODEL);
#pragma unroll
  for (int j = 0; j < 4; j++) {
    ushort4 r;
    r.x = f2bu(xv[j].x); r.y = f2bu(xv[j].y);
    r.z = f2bu(xv[j].z); r.w = f2bu(xv[j].w);
    xbrow[lane + 64 * j] = r;
  }

  float acc[NEXP];
#pragma unroll
  for (int e = 0; e < NEXP; e++) {
    float a = 0.f;
#pragma unroll
    for (int j = 0; j < 4; j++) {
      float4 g = GW4[e * 256 + lane + 64 * j];   // GW = 32KB, L1-hot
      a += xv[j].x * g.x + xv[j].y * g.y + xv[j].z * g.z + xv[j].w * g.w;
    }
    acc[e] = a;
  }
#pragma unroll
  for (int off = 32; off > 0; off >>= 1)
#pragma unroll
    for (int e = 0; e < NEXP; e++) acc[e] += __shfl_down(acc[e], off, 64);

  if (lane == 0) {
    float mx = acc[0];
#pragma unroll
    for (int e = 1; e < NEXP; e++) mx = fmaxf(mx, acc[e]);
    float p[NEXP]; float s = 0.f;
#pragma unroll
    for (int e = 0; e < NEXP; e++) { p[e] = expf(acc[e] - mx); s += p[e]; }
    int i0 = 0;
#pragma unroll
    for (int e = 1; e < NEXP; e++) if (p[e] > p[i0]) i0 = e;
    int i1 = (i0 == 0) ? 1 : 0;
#pragma unroll
    for (int e = 0; e < NEXP; e++) if (e != i1 && e != i0 && p[e] > p[i1]) i1 = e;
    float p0 = p[i0] / s, p1 = p[i1] / s;
    float inv = 1.f / (p0 + p1 + 1e-8f);
    e01[token * 2 + 0] = i0; e01[token * 2 + 1] = i1;
    w01[token * 2 + 0] = p0 * inv; w01[token * 2 + 1] = p1 * inv;
  }
}

// per-block LDS histogram of expert assignments
__global__ void hist_kernel(const int* __restrict__ e01, int* __restrict__ blockCounts) {
  __shared__ int h[NEXP];
  int t = threadIdx.x;
  if (t < NEXP) h[t] = 0;
  __syncthreads();
  int base = blockIdx.x * TOK_PER_PLAN * 2;
  for (int i = t; i < TOK_PER_PLAN * 2; i += 256) atomicAdd(&h[e01[base + i]], 1);
  __syncthreads();
  if (t < NEXP) blockCounts[blockIdx.x * NEXP + t] = h[t];
}

// single thread: expert offsets (128-padded), per-block bases, tile table
__global__ void offsets_kernel(const int* __restrict__ blockCounts, int* __restrict__ blockBase,
                               int* __restrict__ tileExpert, int* __restrict__ nTiles) {
  if (threadIdx.x != 0 || blockIdx.x != 0) return;
  int o = 0, t = 0;
  for (int e = 0; e < NEXP; e++) {
    int run = o, cnt = 0;
    for (int b = 0; b < PLAN_BLOCKS; b++) {
      blockBase[b * NEXP + e] = run;
      run += blockCounts[b * NEXP + e];
      cnt += blockCounts[b * NEXP + e];
    }
    int pad = (cnt + BM - 1) / BM * BM;
    for (int i = 0; i < pad / BM; i++) tileExpert[t++] = e;
    o += pad;
  }
  *nTiles = t;
}

// block-local ranks via LDS atomics (no global contention)
__global__ void scatter_kernel(const int* __restrict__ e01, const float* __restrict__ w01,
                               const int* __restrict__ blockBase,
                               int* __restrict__ row_token, float* __restrict__ row_weight) {
  __shared__ int cur[NEXP];
  __shared__ int base[NEXP];
  int t = threadIdx.x;
  if (t < NEXP) { cur[t] = 0; base[t] = blockBase[blockIdx.x * NEXP + t]; }
  __syncthreads();
  int tb = blockIdx.x * TOK_PER_PLAN;
  for (int i = t; i < TOK_PER_PLAN * 2; i += 256) {
    int e = e01[tb * 2 + i];
    int rank = atomicAdd(&cur[e], 1);
    int pos = base[e] + rank;
    row_token[pos] = tb + (i >> 1);
    row_weight[pos] = w01[tb * 2 + i];
  }
}

// ---------------- GEMM1: A[M,960] = swiglu(X @ Wgu^T), fused gate/up ----------------
__global__ __launch_bounds__(256) void gemm1_swiglu(
    const bf16_t* __restrict__ Xb, const bf16_t* __restrict__ Wgu, long wStride,
    bf16_t* __restrict__ Aout, const int* __restrict__ row_token,
    const int* __restrict__ tileExpert, const int* __restrict__ nTilesPtr) {
  const int mtile = blockIdx.x;
  if (nTilesPtr && mtile >= *nTilesPtr) return;
  const int m0 = mtile * BM;
  const int f0 = blockIdx.y * BN;

  __shared__ bf16_t sA[BM * BK];   // 16KB
  __shared__ bf16_t sBg[BN * BK];  // 8KB
  __shared__ bf16_t sBu[BN * BK];  // 8KB

  const int tid = threadIdx.x;
  const int w = tid >> 6, lane = tid & 63;
  const bf16_t* W = Wgu + (tileExpert ? (long)tileExpert[mtile] * wStride : 0);

  const bf16_t* aptr[4];
#pragma unroll
  for (int i = 0; i < 4; i++) {
    int q = (i * 4 + w) * 64 + lane;
    int row = q >> 3, cc = (q & 7) * 8;
    int tok = m0 + row;
    if (row_token) { int t = row_token[tok]; tok = (t < 0) ? 0 : t; }
    aptr[i] = Xb + (size_t)tok * DMODEL + cc;
  }
  const bf16_t* bgp[2]; const bf16_t* bup[2];
#pragma unroll
  for (int i = 0; i < 2; i++) {
    int q = (i * 4 + w) * 64 + lane;
    int r = q >> 3, cc = (q & 7) * 8;
    bgp[i] = W + (size_t)(f0 + r) * DMODEL + cc;
    bup[i] = W + (size_t)(INTER + f0 + r) * DMODEL + cc;
  }

  f32x4 accG[4][2], accU[4][2];
#pragma unroll
  for (int mi = 0; mi < 4; mi++)
#pragma unroll
    for (int ni = 0; ni < 2; ni++) {
      accG[mi][ni] = (f32x4){0.f, 0.f, 0.f, 0.f};
      accU[mi][ni] = (f32x4){0.f, 0.f, 0.f, 0.f};
    }

  const int wm = w >> 1, wn = w & 1;
  const int lr = lane & 15, quad = lane >> 4;

  for (int k0 = 0; k0 < DMODEL; k0 += BK) {
#pragma unroll
    for (int i = 0; i < 4; i++) async16(aptr[i] + k0, &sA[(i * 4 + w) * 512]);
#pragma unroll
    for (int i = 0; i < 2; i++) {
      async16(bgp[i] + k0, &sBg[(i * 4 + w) * 512]);
      async16(bup[i] + k0, &sBu[(i * 4 + w) * 512]);
    }
    __syncthreads();
#pragma unroll
    for (int kk = 0; kk < BK; kk += 32) {
      bf16x8 av[4], bg[2], bu[2];
#pragma unroll
      for (int mi = 0; mi < 4; mi++)
        av[mi] = *(const bf16x8*)&sA[(wm * 64 + mi * 16 + lr) * BK + kk + quad * 8];
#pragma unroll
      for (int ni = 0; ni < 2; ni++) {
        bg[ni] = *(const bf16x8*)&sBg[(wn * 32 + ni * 16 + lr) * BK + kk + quad * 8];
        bu[ni] = *(const bf16x8*)&sBu[(wn * 32 + ni * 16 + lr) * BK + kk + quad * 8];
      }
#pragma unroll
      for (int mi = 0; mi < 4; mi++)
#pragma unroll
        for (int ni = 0; ni < 2; ni++) {
          accG[mi][ni] = __builtin_amdgcn_mfma_f32_16x16x32_bf16(av[mi], bg[ni], accG[mi][ni], 0, 0, 0);
          accU[mi][ni] = __builtin_amdgcn_mfma_f32_16x16x32_bf16(av[mi], bu[ni], accU[mi][ni], 0, 0, 0);
        }
    }
    __syncthreads();
  }

  // epilogue: C/D layout col=lane&15, row=quad*4+reg
#pragma unroll
  for (int mi = 0; mi < 4; mi++)
#pragma unroll
    for (int ni = 0; ni < 2; ni++)
#pragma unroll
      for (int r = 0; r < 4; r++) {
        int row = m0 + wm * 64 + mi * 16 + quad * 4 + r;
        int col = f0 + wn * 32 + ni * 16 + lr;
        float g = accG[mi][ni][r], u = accU[mi][ni][r];
        float v = (col < INTER) ? (g / (1.f + __expf(-g))) * u : 0.f;
        Aout[(size_t)row * IPAD + col] = (bf16_t)v;
      }
}

// ---------------- GEMM2: Out[M,1024] (+)= A[M,960] @ Wd^T ----------------
__global__ __launch_bounds__(256) void gemm2(
    const bf16_t* __restrict__ Ain, const bf16_t* __restrict__ Wd, long wStride,
    float* __restrict__ Out, const int* __restrict__ row_token,
    const float* __restrict__ row_weight, const int* __restrict__ tileExpert,
    const int* __restrict__ nTilesPtr) {
  const int mtile = blockIdx.x;
  if (nTilesPtr && mtile >= *nTilesPtr) return;
  const int m0 = mtile * BM;
  const int n0 = blockIdx.y * BN;

  __shared__ bf16_t sA[BM * BK];
  __shared__ bf16_t sB[BN * BK];

  const int tid = threadIdx.x;
  const int w = tid >> 6, lane = tid & 63;
  const bf16_t* W = Wd + (tileExpert ? (long)tileExpert[mtile] * wStride : 0);

  const bf16_t* aptr[4];
#pragma unroll
  for (int i = 0; i < 4; i++) {
    int q = (i * 4 + w) * 64 + lane;
    int row = q >> 3, cc = (q & 7) * 8;
    aptr[i] = Ain + (size_t)(m0 + row) * IPAD + cc;
  }
  const bf16_t* bp[2];
#pragma unroll
  for (int i = 0; i < 2; i++) {
    int q = (i * 4 + w) * 64 + lane;
    int r = q >> 3, cc = (q & 7) * 8;
    bp[i] = W + (size_t)(n0 + r) * IPAD + cc;
  }

  f32x4 acc[4][2];
#pragma unroll
  for (int mi = 0; mi < 4; mi++)
#pragma unroll
    for (int ni = 0; ni < 2; ni++) acc[mi][ni] = (f32x4){0.f, 0.f, 0.f, 0.f};

  const int wm = w >> 1, wn = w & 1;
  const int lr = lane & 15, quad = lane >> 4;

  for (int k0 = 0; k0 < IPAD; k0 += BK) {
#pragma unroll
    for (int i = 0; i < 4; i++) async16(aptr[i] + k0, &sA[(i * 4 + w) * 512]);
#pragma unroll
    for (int i = 0; i < 2; i++) async16(bp[i] + k0, &sB[(i * 4 + w) * 512]);
    __syncthreads();
#pragma unroll
    for (int kk = 0; kk < BK; kk += 32) {
      bf16x8 av[4], bv[2];
#pragma unroll
      for (int mi = 0; mi < 4; mi++)
        av[mi] = *(const bf16x8*)&sA[(wm * 64 + mi * 16 + lr) * BK + kk + quad * 8];
#pragma unroll
      for (int ni = 0; ni < 2; ni++)
        bv[ni] = *(const bf16x8*)&sB[(wn * 32 + ni * 16 + lr) * BK + kk + quad * 8];
#pragma unroll
      for (int mi = 0; mi < 4; mi++)
#pragma unroll
        for (int ni = 0; ni < 2; ni++)
          acc[mi][ni] = __builtin_amdgcn_mfma_f32_16x16x32_bf16(av[mi], bv[ni], acc[mi][ni], 0, 0, 0);
    }
    __syncthreads();
  }

#pragma unroll
  for (int mi = 0; mi < 4; mi++)
#pragma unroll
    for (int ni = 0; ni < 2; ni++)
#pragma unroll
      for (int r = 0; r < 4; r++) {
        int row = m0 + wm * 64 + mi * 16 + quad * 4 + r;
        int col = n0 + wn * 32 + ni * 16 + lr;
        float v = acc[mi][ni][r];
        if (!row_token) {
          Out[(size_t)row * DMODEL + col] = v;
        } else {
          int t = row_token[row];
          if (t >= 0) atomicAdd(&Out[(size_t)t * DMODEL + col], row_weight[row] * v);
        }
      }
}

// ---------------- launch ----------------
extern "C" void kernel_launch(void* const* d_in, const int* in_sizes, int n_in,
                              void* d_out, int out_size, void* d_ws, size_t ws_size,
                              hipStream_t stream) {
  const float* X   = (const float*)d_in[0];
  const float* GW  = (const float*)d_in[1];
  const float* SGU = (const float*)d_in[2];
  const float* SD  = (const float*)d_in[3];
  const float* EGU = (const float*)d_in[4];
  const float* ED  = (const float*)d_in[5];
  float* Out = (float*)d_out;

  char* ws = (char*)d_ws;
  size_t o = 0;
  auto alloc = [&](size_t b) -> char* {
    char* p = ws + o;
    o = (o + b + 255) & ~(size_t)255;
    return p;
  };
  bf16_t* Xb     = (bf16_t*)alloc((size_t)TOKENS * DMODEL * 2);
  bf16_t* WguS   = (bf16_t*)alloc((size_t)1920 * DMODEL * 2);
  bf16_t* WdS    = (bf16_t*)alloc((size_t)DMODEL * IPAD * 2);
  bf16_t* WguE   = (bf16_t*)alloc((size_t)NEXP * GU_ROWS * DMODEL * 2 + 65536);
  bf16_t* WdE    = (bf16_t*)alloc((size_t)NEXP * DMODEL * IPAD * 2);
  bf16_t* As     = (bf16_t*)alloc((size_t)TOKENS * IPAD * 2);
  bf16_t* Ar     = (bf16_t*)alloc((size_t)CAP_ROWS * IPAD * 2);
  int*    e01    = (int*)alloc(TOKENS * 2 * 4);
  float*  w01    = (float*)alloc(TOKENS * 2 * 4);
  int*    blkCnt = (int*)alloc(PLAN_BLOCKS * NEXP * 4);
  int*    blkBas = (int*)alloc(PLAN_BLOCKS * NEXP * 4);
  int*    nTiles = (int*)alloc(64);
  int*    tileEx = (int*)alloc(MAX_TILES * 4);
  int*    rowTok = (int*)alloc(CAP_ROWS * 4);
  float*  rowW   = (float*)alloc(CAP_ROWS * 4);
  (void)ws_size; (void)in_sizes; (void)n_in; (void)out_size;

  // weight conversions (X conversion now fused into router)
  conv_f2b<<<(480256 + 255) / 256, 256, 0, stream>>>((const float4*)SGU, (ushort4*)WguS, 480256);
  conv_f2b<<<(3842048 + 255) / 256, 256, 0, stream>>>((const float4*)EGU, (ushort4*)WguE, 3842048);
  conv_down<<<(DMODEL * IPAD + 255) / 256, 256, 0, stream>>>(SD, WdS, DMODEL);
  conv_down<<<(NEXP * DMODEL * IPAD + 255) / 256, 256, 0, stream>>>(ED, WdE, NEXP * DMODEL);

  // routing
  init_kernel<<<(CAP_ROWS + 255) / 256, 256, 0, stream>>>(rowTok);
  router_kernel<<<TOKENS / 4, 256, 0, stream>>>(
      (const float4*)X, (const float4*)GW, Xb, e01, w01);
  hist_kernel<<<PLAN_BLOCKS, 256, 0, stream>>>(e01, blkCnt);
  offsets_kernel<<<1, 64, 0, stream>>>(blkCnt, blkBas, tileEx, nTiles);
  scatter_kernel<<<PLAN_BLOCKS, 256, 0, stream>>>(e01, w01, blkBas, rowTok, rowW);

  // GEMMs
  gemm1_swiglu<<<dim3(TOKENS / BM, IPAD / BN), 256, 0, stream>>>(
      Xb, WguS, 0, As, nullptr, nullptr, nullptr);
  gemm1_swiglu<<<dim3(MAX_TILES, IPAD / BN), 256, 0, stream>>>(
      Xb, WguE, (long)GU_ROWS * DMODEL, Ar, rowTok, tileEx, nTiles);
  gemm2<<<dim3(TOKENS / BM, DMODEL / BN), 256, 0, stream>>>(
      As, WdS, 0, Out, nullptr, nullptr, nullptr, nullptr);
  gemm2<<<dim3(MAX_TILES, DMODEL / BN), 256, 0, stream>>>(
      Ar, WdE, (long)DMODEL * IPAD, Out, rowTok, rowW, tileEx, nTiles);
}

// Round 3
// 456.447 us; speedup vs baseline: 1.6843x; 1.1406x over previous
//
#include <hip/hip_runtime.h>
#include <hip/hip_bf16.h>
#include <stdint.h>

// MoE: B=4,S=2048,D=1024,E=8,TOPK=2,I=938. Sparse top-2 routing + bf16 MFMA GEMMs.
// R3: gemm2 -> 128x128 tile (m97 ratio), atomics replaced by Yr+combine,
//     XOR LDS swizzle (bank-conflict-free), all strides padded to 1024.

typedef __bf16 bf16_t;
typedef __bf16 bf16x8 __attribute__((ext_vector_type(8)));
typedef float  f32x4  __attribute__((ext_vector_type(4)));

#define TOKENS    8192
#define DMODEL    1024
#define NEXP      8
#define INTER     938
#define AP        1024     // padded inter dim (A cols / gemm2 K / Wd cols)
#define GUP       2048     // padded gate(1024)+up(1024) rows per expert
#define CAP_ROWS  17408    // 16384 + 8*128
#define MAX_TILES 136
#define SH_TILES  64       // 8192/128
#define BM        128
#define BK        64

#define PLAN_BLOCKS 16
#define TOK_PER_PLAN (TOKENS / PLAN_BLOCKS)

// ---- async global->LDS, 16B per lane; LDS dest = wave-uniform base + lane*16 ----
__device__ __forceinline__ void async16(const bf16_t* g, bf16_t* l) {
  __builtin_amdgcn_global_load_lds(
      (__attribute__((address_space(1))) void*)(g),
      (__attribute__((address_space(3))) void*)(l),
      16, 0, 0);
}

__device__ __forceinline__ unsigned short f2bu(float f) {
  bf16_t b = (bf16_t)f;
  unsigned short u;
  __builtin_memcpy(&u, &b, 2);
  return u;
}

// ---------------- weight re-layout converts ----------------
// gate_up [nExp,1876,1024] fp32 -> [nExp,2048,1024] bf16: rows 0..937 gate,
// 938..1023 zero, 1024..1961 up (src row r-86), 1962..2047 zero.
__global__ void conv_gu_pad(const float4* __restrict__ src, ushort4* __restrict__ dst) {
  int i = blockIdx.x * 256 + threadIdx.x;
  int e = i >> 19;            // GUP*256 = 2^19
  int rem = i & 524287;
  int r = rem >> 8;
  int c4 = rem & 255;
  const float4* s = src + (size_t)e * (1876 * 256);
  float4 v = {0.f, 0.f, 0.f, 0.f};
  if (r < INTER) v = s[r * 256 + c4];
  else if (r >= 1024 && r < 1024 + INTER) v = s[(r - 86) * 256 + c4];
  ushort4 o;
  o.x = f2bu(v.x); o.y = f2bu(v.y); o.z = f2bu(v.z); o.w = f2bu(v.w);
  dst[i] = o;
}

// down [nExp,1024,938] fp32 -> [nExp,1024,1024] bf16, cols >=938 zero
__global__ void conv_dn_pad(const float* __restrict__ src, bf16_t* __restrict__ dst) {
  int i = blockIdx.x * 256 + threadIdx.x;
  int e = i >> 20;
  int rem = i & 1048575;
  int n = rem >> 10;
  int c = rem & 1023;
  float v = (c < INTER) ? src[(size_t)e * (1024 * INTER) + n * INTER + c] : 0.f;
  dst[i] = (bf16_t)v;
}

// ---------------- routing ----------------
__global__ void init_kernel(int* __restrict__ row_token) {
  int i = blockIdx.x * 256 + threadIdx.x;
  if (i < CAP_ROWS) row_token[i] = -1;
}

// one wave per token: fp32 logits with full ILP, top-2, no atomics; emits Xb bf16.
__global__ __launch_bounds__(256) void router_kernel(
    const float4* __restrict__ X4, const float4* __restrict__ GW4,
    bf16_t* __restrict__ Xb, int* __restrict__ e01, float* __restrict__ w01) {
  int token = blockIdx.x * 4 + (threadIdx.x >> 6);
  int lane = threadIdx.x & 63;
  const float4* x4 = X4 + (size_t)token * 256;

  float4 xv[4];
#pragma unroll
  for (int j = 0; j < 4; j++) xv[j] = x4[lane + 64 * j];

  ushort4* xbrow = (ushort4*)(Xb + (size_t)token * DMODEL);
#pragma unroll
  for (int j = 0; j < 4; j++) {
    ushort4 r;
    r.x = f2bu(xv[j].x); r.y = f2bu(xv[j].y);
    r.z = f2bu(xv[j].z); r.w = f2bu(xv[j].w);
    xbrow[lane + 64 * j] = r;
  }

  float acc[NEXP];
#pragma unroll
  for (int e = 0; e < NEXP; e++) {
    float a = 0.f;
#pragma unroll
    for (int j = 0; j < 4; j++) {
      float4 g = GW4[e * 256 + lane + 64 * j];
      a += xv[j].x * g.x + xv[j].y * g.y + xv[j].z * g.z + xv[j].w * g.w;
    }
    acc[e] = a;
  }
#pragma unroll
  for (int off = 32; off > 0; off >>= 1)
#pragma unroll
    for (int e = 0; e < NEXP; e++) acc[e] += __shfl_down(acc[e], off, 64);

  if (lane == 0) {
    float mx = acc[0];
#pragma unroll
    for (int e = 1; e < NEXP; e++) mx = fmaxf(mx, acc[e]);
    float p[NEXP]; float s = 0.f;
#pragma unroll
    for (int e = 0; e < NEXP; e++) { p[e] = expf(acc[e] - mx); s += p[e]; }
    int i0 = 0;
#pragma unroll
    for (int e = 1; e < NEXP; e++) if (p[e] > p[i0]) i0 = e;
    int i1 = (i0 == 0) ? 1 : 0;
#pragma unroll
    for (int e = 0; e < NEXP; e++) if (e != i1 && e != i0 && p[e] > p[i1]) i1 = e;
    float p0 = p[i0] / s, p1 = p[i1] / s;
    float inv = 1.f / (p0 + p1 + 1e-8f);
    e01[token * 2 + 0] = i0; e01[token * 2 + 1] = i1;
    w01[token * 2 + 0] = p0 * inv; w01[token * 2 + 1] = p1 * inv;
  }
}

__global__ void hist_kernel(const int* __restrict__ e01, int* __restrict__ blockCounts) {
  __shared__ int h[NEXP];
  int t = threadIdx.x;
  if (t < NEXP) h[t] = 0;
  __syncthreads();
  int base = blockIdx.x * TOK_PER_PLAN * 2;
  for (int i = t; i < TOK_PER_PLAN * 2; i += 256) atomicAdd(&h[e01[base + i]], 1);
  __syncthreads();
  if (t < NEXP) blockCounts[blockIdx.x * NEXP + t] = h[t];
}

__global__ void offsets_kernel(const int* __restrict__ blockCounts, int* __restrict__ blockBase,
                               int* __restrict__ tileExpert, int* __restrict__ nTiles) {
  if (threadIdx.x != 0 || blockIdx.x != 0) return;
  int o = 0, t = 0;
  for (int e = 0; e < NEXP; e++) {
    int run = o, cnt = 0;
    for (int b = 0; b < PLAN_BLOCKS; b++) {
      blockBase[b * NEXP + e] = run;
      run += blockCounts[b * NEXP + e];
      cnt += blockCounts[b * NEXP + e];
    }
    int pad = (cnt + BM - 1) / BM * BM;
    for (int i = 0; i < pad / BM; i++) tileExpert[t++] = e;
    o += pad;
  }
  *nTiles = t;
}

// block-local ranks via LDS atomics; also emits slotOf (token -> its 2 slot rows)
__global__ void scatter_kernel(const int* __restrict__ e01, const float* __restrict__ w01,
                               const int* __restrict__ blockBase,
                               int* __restrict__ row_token, float* __restrict__ row_weight,
                               int* __restrict__ slotOf) {
  __shared__ int cur[NEXP];
  __shared__ int base[NEXP];
  int t = threadIdx.x;
  if (t < NEXP) { cur[t] = 0; base[t] = blockBase[blockIdx.x * NEXP + t]; }
  __syncthreads();
  int tb = blockIdx.x * TOK_PER_PLAN;
  for (int i = t; i < TOK_PER_PLAN * 2; i += 256) {
    int e = e01[tb * 2 + i];
    int rank = atomicAdd(&cur[e], 1);
    int pos = base[e] + rank;
    row_token[pos] = tb + (i >> 1);
    row_weight[pos] = w01[tb * 2 + i];
    slotOf[tb * 2 + i] = pos;
  }
}

// ---------------- GEMM1 (fused shared+routed): A[M,1024] = swiglu(X @ Wgu^T) ----------------
// tile 128 x (64 gate + 64 up), BK=64; 4 waves 2x2; XOR-swizzled LDS.
__global__ __launch_bounds__(256) void gemm1_fused(
    const bf16_t* __restrict__ Xb, const bf16_t* __restrict__ WS,
    const bf16_t* __restrict__ WE, bf16_t* __restrict__ As, bf16_t* __restrict__ Ar,
    const int* __restrict__ row_token, const int* __restrict__ tileExpert,
    const int* __restrict__ nTilesPtr) {
  const int mt = blockIdx.x;
  const bf16_t* W; bf16_t* Aout; int m0; const int* rtok = nullptr;
  if (mt < SH_TILES) {
    m0 = mt * BM; W = WS; Aout = As;
  } else {
    int rt = mt - SH_TILES;
    if (rt >= *nTilesPtr) return;
    m0 = rt * BM; W = WE + (size_t)tileExpert[rt] * (GUP * DMODEL);
    Aout = Ar; rtok = row_token;
  }
  const int f0 = blockIdx.y * 64;

  __shared__ bf16_t sA[BM * BK];    // 16KB
  __shared__ bf16_t sBg[64 * BK];   // 8KB
  __shared__ bf16_t sBu[64 * BK];   // 8KB

  const int tid = threadIdx.x;
  const int w = tid >> 6, lane = tid & 63;

  const bf16_t* aptr[4];
#pragma unroll
  for (int i = 0; i < 4; i++) {
    int q = (i * 4 + w) * 64 + lane;
    int row = q >> 3, cc = ((q & 7) ^ (row & 7)) * 8;   // XOR swizzle
    int tok = m0 + row;
    if (rtok) { int t = rtok[tok]; tok = (t < 0) ? 0 : t; }
    aptr[i] = Xb + (size_t)tok * DMODEL + cc;
  }
  const bf16_t* bgp[2]; const bf16_t* bup[2];
#pragma unroll
  for (int i = 0; i < 2; i++) {
    int q = (i * 4 + w) * 64 + lane;
    int r = q >> 3, cc = ((q & 7) ^ (r & 7)) * 8;
    bgp[i] = W + (size_t)(f0 + r) * DMODEL + cc;
    bup[i] = W + (size_t)(1024 + f0 + r) * DMODEL + cc;
  }

  f32x4 accG[4][2], accU[4][2];
#pragma unroll
  for (int mi = 0; mi < 4; mi++)
#pragma unroll
    for (int ni = 0; ni < 2; ni++) {
      accG[mi][ni] = (f32x4){0.f, 0.f, 0.f, 0.f};
      accU[mi][ni] = (f32x4){0.f, 0.f, 0.f, 0.f};
    }

  const int wm = w >> 1, wn = w & 1;
  const int lr = lane & 15, quad = lane >> 4;

  for (int k0 = 0; k0 < DMODEL; k0 += BK) {
#pragma unroll
    for (int i = 0; i < 4; i++) async16(aptr[i] + k0, &sA[(i * 4 + w) * 512]);
#pragma unroll
    for (int i = 0; i < 2; i++) {
      async16(bgp[i] + k0, &sBg[(i * 4 + w) * 512]);
      async16(bup[i] + k0, &sBu[(i * 4 + w) * 512]);
    }
    __syncthreads();
#pragma unroll
    for (int kk = 0; kk < BK; kk += 32) {
      const int colsw = (((kk >> 3) + quad) ^ (lr & 7)) * 8;
      bf16x8 av[4], bg[2], bu[2];
#pragma unroll
      for (int mi = 0; mi < 4; mi++)
        av[mi] = *(const bf16x8*)&sA[(wm * 64 + mi * 16 + lr) * BK + colsw];
#pragma unroll
      for (int ni = 0; ni < 2; ni++) {
        bg[ni] = *(const bf16x8*)&sBg[(wn * 32 + ni * 16 + lr) * BK + colsw];
        bu[ni] = *(const bf16x8*)&sBu[(wn * 32 + ni * 16 + lr) * BK + colsw];
      }
#pragma unroll
      for (int mi = 0; mi < 4; mi++)
#pragma unroll
        for (int ni = 0; ni < 2; ni++) {
          accG[mi][ni] = __builtin_amdgcn_mfma_f32_16x16x32_bf16(av[mi], bg[ni], accG[mi][ni], 0, 0, 0);
          accU[mi][ni] = __builtin_amdgcn_mfma_f32_16x16x32_bf16(av[mi], bu[ni], accU[mi][ni], 0, 0, 0);
        }
    }
    __syncthreads();
  }

  // C/D layout: col=lane&15, row=quad*4+reg
#pragma unroll
  for (int mi = 0; mi < 4; mi++)
#pragma unroll
    for (int ni = 0; ni < 2; ni++)
#pragma unroll
      for (int r = 0; r < 4; r++) {
        int row = m0 + wm * 64 + mi * 16 + quad * 4 + r;
        int col = f0 + wn * 32 + ni * 16 + lr;
        float g = accG[mi][ni][r], u = accU[mi][ni][r];
        float v = (col < INTER) ? (g / (1.f + __expf(-g))) * u : 0.f;
        Aout[(size_t)row * AP + col] = (bf16_t)v;
      }
}

// ---------------- GEMM2 (fused shared+routed): 128x128 tile ----------------
// shared: Out[row,1024] = A @ Wd^T (plain fp32 stores)
// routed: Yr[slot,1024] = w * (A @ Wd^T)  (bf16 stores, no atomics)
__global__ __launch_bounds__(256) void gemm2_fused(
    const bf16_t* __restrict__ As, const bf16_t* __restrict__ Ar,
    const bf16_t* __restrict__ WS, const bf16_t* __restrict__ WE,
    float* __restrict__ Out, bf16_t* __restrict__ Yr,
    const float* __restrict__ row_weight, const int* __restrict__ tileExpert,
    const int* __restrict__ nTilesPtr) {
  const int mt = blockIdx.x;
  const bf16_t* A; const bf16_t* W; int m0; bool routed;
  if (mt < SH_TILES) {
    routed = false; m0 = mt * BM; A = As; W = WS;
  } else {
    int rt = mt - SH_TILES;
    if (rt >= *nTilesPtr) return;
    routed = true; m0 = rt * BM; A = Ar;
    W = WE + (size_t)tileExpert[rt] * (DMODEL * AP);
  }
  const int n0 = blockIdx.y * 128;

  __shared__ bf16_t sA[BM * BK];   // 16KB
  __shared__ bf16_t sB[128 * BK];  // 16KB

  const int tid = threadIdx.x;
  const int w = tid >> 6, lane = tid & 63;

  const bf16_t* aptr[4];
#pragma unroll
  for (int i = 0; i < 4; i++) {
    int q = (i * 4 + w) * 64 + lane;
    int row = q >> 3, cc = ((q & 7) ^ (row & 7)) * 8;
    aptr[i] = A + (size_t)(m0 + row) * AP + cc;
  }
  const bf16_t* bp[4];
#pragma unroll
  for (int i = 0; i < 4; i++) {
    int q = (i * 4 + w) * 64 + lane;
    int r = q >> 3, cc = ((q & 7) ^ (r & 7)) * 8;
    bp[i] = W + (size_t)(n0 + r) * AP + cc;
  }

  f32x4 acc[4][4];
#pragma unroll
  for (int mi = 0; mi < 4; mi++)
#pragma unroll
    for (int ni = 0; ni < 4; ni++) acc[mi][ni] = (f32x4){0.f, 0.f, 0.f, 0.f};

  const int wm = w >> 1, wn = w & 1;
  const int lr = lane & 15, quad = lane >> 4;

  for (int k0 = 0; k0 < AP; k0 += BK) {
#pragma unroll
    for (int i = 0; i < 4; i++) async16(aptr[i] + k0, &sA[(i * 4 + w) * 512]);
#pragma unroll
    for (int i = 0; i < 4; i++) async16(bp[i] + k0, &sB[(i * 4 + w) * 512]);
    __syncthreads();
#pragma unroll
    for (int kk = 0; kk < BK; kk += 32) {
      const int colsw = (((kk >> 3) + quad) ^ (lr & 7)) * 8;
      bf16x8 av[4], bv[4];
#pragma unroll
      for (int mi = 0; mi < 4; mi++)
        av[mi] = *(const bf16x8*)&sA[(wm * 64 + mi * 16 + lr) * BK + colsw];
#pragma unroll
      for (int ni = 0; ni < 4; ni++)
        bv[ni] = *(const bf16x8*)&sB[(wn * 64 + ni * 16 + lr) * BK + colsw];
#pragma unroll
      for (int mi = 0; mi < 4; mi++)
#pragma unroll
        for (int ni = 0; ni < 4; ni++)
          acc[mi][ni] = __builtin_amdgcn_mfma_f32_16x16x32_bf16(av[mi], bv[ni], acc[mi][ni], 0, 0, 0);
    }
    __syncthreads();
  }

#pragma unroll
  for (int mi = 0; mi < 4; mi++) {
#pragma unroll
    for (int r = 0; r < 4; r++) {
      int row = m0 + wm * 64 + mi * 16 + quad * 4 + r;
      float rw = routed ? row_weight[row] : 0.f;
#pragma unroll
      for (int ni = 0; ni < 4; ni++) {
        int col = n0 + wn * 64 + ni * 16 + lr;
        float v = acc[mi][ni][r];
        if (!routed) Out[(size_t)row * DMODEL + col] = v;
        else         Yr[(size_t)row * DMODEL + col] = (bf16_t)(rw * v);
      }
    }
  }
}

// ---------------- combine: Out[t] += Yr[slot0(t)] + Yr[slot1(t)] ----------------
__global__ __launch_bounds__(256) void combine_kernel(
    float4* __restrict__ Out4, const ushort4* __restrict__ Yr4,
    const int* __restrict__ slotOf) {
  int t = blockIdx.x;
  int c = threadIdx.x;
  int s0 = slotOf[t * 2 + 0];
  int s1 = slotOf[t * 2 + 1];
  float4 o = Out4[t * 256 + c];
  ushort4 a = Yr4[(size_t)s0 * 256 + c];
  ushort4 b = Yr4[(size_t)s1 * 256 + c];
  union { unsigned int u; float f; } cv;
  auto b2f = [&](unsigned short x) { cv.u = ((unsigned int)x) << 16; return cv.f; };
  o.x += b2f(a.x) + b2f(b.x);
  o.y += b2f(a.y) + b2f(b.y);
  o.z += b2f(a.z) + b2f(b.z);
  o.w += b2f(a.w) + b2f(b.w);
  Out4[t * 256 + c] = o;
}

// ---------------- launch ----------------
extern "C" void kernel_launch(void* const* d_in, const int* in_sizes, int n_in,
                              void* d_out, int out_size, void* d_ws, size_t ws_size,
                              hipStream_t stream) {
  const float* X   = (const float*)d_in[0];
  const float* GW  = (const float*)d_in[1];
  const float* SGU = (const float*)d_in[2];
  const float* SD  = (const float*)d_in[3];
  const float* EGU = (const float*)d_in[4];
  const float* ED  = (const float*)d_in[5];
  float* Out = (float*)d_out;

  char* ws = (char*)d_ws;
  size_t o = 0;
  auto alloc = [&](size_t b) -> char* {
    char* p = ws + o;
    o = (o + b + 255) & ~(size_t)255;
    return p;
  };
  bf16_t* Xb    = (bf16_t*)alloc((size_t)TOKENS * DMODEL * 2);          // 16.8 MB
  bf16_t* WguSP = (bf16_t*)alloc((size_t)GUP * DMODEL * 2);             // 4.2 MB
  bf16_t* WdSP  = (bf16_t*)alloc((size_t)DMODEL * AP * 2);              // 2.1 MB
  bf16_t* WguEP = (bf16_t*)alloc((size_t)NEXP * GUP * DMODEL * 2);      // 33.6 MB
  bf16_t* WdEP  = (bf16_t*)alloc((size_t)NEXP * DMODEL * AP * 2);       // 16.8 MB
  bf16_t* As    = (bf16_t*)alloc((size_t)TOKENS * AP * 2);              // 16.8 MB
  bf16_t* Ar    = (bf16_t*)alloc((size_t)CAP_ROWS * AP * 2);            // 35.7 MB
  bf16_t* Yr    = (bf16_t*)alloc((size_t)CAP_ROWS * DMODEL * 2);        // 35.7 MB
  int*    e01    = (int*)alloc(TOKENS * 2 * 4);
  float*  w01    = (float*)alloc(TOKENS * 2 * 4);
  int*    slotOf = (int*)alloc(TOKENS * 2 * 4);
  int*    blkCnt = (int*)alloc(PLAN_BLOCKS * NEXP * 4);
  int*    blkBas = (int*)alloc(PLAN_BLOCKS * NEXP * 4);
  int*    nTiles = (int*)alloc(64);
  int*    tileEx = (int*)alloc(MAX_TILES * 4);
  int*    rowTok = (int*)alloc(CAP_ROWS * 4);
  float*  rowW   = (float*)alloc(CAP_ROWS * 4);
  (void)ws_size; (void)in_sizes; (void)n_in; (void)out_size;

  // weight re-layout (padded): shared uses same kernels with 1 "expert"
  conv_gu_pad<<<2048, 256, 0, stream>>>((const float4*)SGU, (ushort4*)WguSP);
  conv_gu_pad<<<NEXP * 2048, 256, 0, stream>>>((const float4*)EGU, (ushort4*)WguEP);
  conv_dn_pad<<<4096, 256, 0, stream>>>(SD, WdSP);
  conv_dn_pad<<<NEXP * 4096, 256, 0, stream>>>(ED, WdEP);

  // routing
  init_kernel<<<(CAP_ROWS + 255) / 256, 256, 0, stream>>>(rowTok);
  router_kernel<<<TOKENS / 4, 256, 0, stream>>>(
      (const float4*)X, (const float4*)GW, Xb, e01, w01);
  hist_kernel<<<PLAN_BLOCKS, 256, 0, stream>>>(e01, blkCnt);
  offsets_kernel<<<1, 64, 0, stream>>>(blkCnt, blkBas, tileEx, nTiles);
  scatter_kernel<<<PLAN_BLOCKS, 256, 0, stream>>>(e01, w01, blkBas, rowTok, rowW, slotOf);

  // GEMMs (shared + routed fused in one grid each)
  gemm1_fused<<<dim3(SH_TILES + MAX_TILES, DMODEL / 64), 256, 0, stream>>>(
      Xb, WguSP, WguEP, As, Ar, rowTok, tileEx, nTiles);
  gemm2_fused<<<dim3(SH_TILES + MAX_TILES, DMODEL / 128), 256, 0, stream>>>(
      As, Ar, WdSP, WdEP, Out, Yr, rowW, tileEx, nTiles);
  combine_kernel<<<TOKENS, 256, 0, stream>>>((float4*)Out, (const ushort4*)Yr, slotOf);
}